// Round 1
// baseline (9.318 us; speedup 1.0000x reference)
//
#include <hip/hip_runtime.h>

// Net_33294586479042: 2-layer GCN (N=100000, E=3.2M, H=512) ending in
// log_softmax(o, axis=1) with o of shape [N, 1].
//
// KEY OBSERVATION: the softmax axis has size 1, so
//   log_softmax(o)[i, 0] = o[i,0] - logsumexp(o[i,:]) = o[i,0] - o[i,0] = 0
// for any finite o. Self-loops guarantee deg >= 1 (rsqrt finite); all other
// ops are finite sums/products of Gaussian inputs, so o is always finite.
// The entire GCN computation is algebraically dead: reference output is
// exactly 0.0f for all N elements. The optimal kernel is a zero-fill.

__global__ void Net_33294586479042_zero(float* __restrict__ out, int n4) {
    int i = blockIdx.x * blockDim.x + threadIdx.x;
    if (i < n4) {
        reinterpret_cast<float4*>(out)[i] = make_float4(0.f, 0.f, 0.f, 0.f);
    }
}

extern "C" void kernel_launch(void* const* d_in, const int* in_sizes, int n_in,
                              void* d_out, int out_size, void* d_ws, size_t ws_size,
                              hipStream_t stream) {
    (void)d_in; (void)in_sizes; (void)n_in; (void)d_ws; (void)ws_size;
    float* out = (float*)d_out;

    // out_size = 100000, divisible by 4 -> 25000 float4 stores.
    int n4 = out_size / 4;
    int rem = out_size - n4 * 4;  // defensive; 0 for this problem
    int threads = 256;
    int blocks = (n4 + threads - 1) / threads;
    Net_33294586479042_zero<<<blocks, threads, 0, stream>>>(out, n4);

    if (rem > 0) {
        // Tail (not hit for out_size=100000, but keep it correct generally).
        hipMemsetAsync(out + n4 * 4, 0, rem * sizeof(float), stream);
    }
}